// Round 8
// baseline (263.531 us; speedup 1.0000x reference)
//
#include <hip/hip_runtime.h>
#include <hip/hip_bf16.h>
#include <hip/hip_fp16.h>

#define USER_NUM 100000
#define ITEM_NUM 50000
#define NNODES   150000
#define DIM      64
#define NEDGES   2400000
#define BATCH    4096

#define SPN      1024                           // nodes per super-bucket (dst>>10)
#define NSUP     ((NNODES + SPN - 1) / SPN)     // 147 super-buckets
#define CHUNK    2048
#define NBLK     ((NEDGES + CHUNK - 1) / CHUNK) // 1172 blocks

__device__ inline float4 h4_to_f4(float2 raw) {
    __half2 a = ((__half2*)&raw)[0];
    __half2 b = ((__half2*)&raw)[1];
    float2 fa = __half22float2(a);
    float2 fb = __half22float2(b);
    return make_float4(fa.x, fa.y, fb.x, fb.y);
}

__device__ inline float2 f4_to_h4(float4 s) {
    __half2 a = __floats2half2_rn(s.x, s.y);
    __half2 b = __floats2half2_rn(s.z, s.w);
    float2 st;
    ((__half2*)&st)[0] = a;
    ((__half2*)&st)[1] = b;
    return st;
}

// ---------------------------------------------------------------------------
// init: tabA = concat(user_emb, item_emb) in fp16
// ---------------------------------------------------------------------------
__global__ void init_kernel(const float* __restrict__ user_emb,
                            const float* __restrict__ item_emb,
                            __half* __restrict__ curh) {
    const long total4 = (long)NNODES * DIM / 4;
    long i = (long)blockIdx.x * blockDim.x + threadIdx.x;
    if (i >= total4) return;
    const long user4 = (long)USER_NUM * DIM / 4;
    float4 v;
    if (i < user4) v = ((const float4*)user_emb)[i];
    else           v = ((const float4*)item_emb)[i - user4];
    ((float2*)curh)[i] = f4_to_h4(v);
}

// ---------------------------------------------------------------------------
// sampled acc init: acc_s[slot] = e0 at sampled node (fp32 from orig emb)
// ---------------------------------------------------------------------------
__global__ void sample_init_kernel(const float* __restrict__ user_emb,
                                   const float* __restrict__ item_emb,
                                   const int* __restrict__ users,
                                   const int* __restrict__ items,
                                   float* __restrict__ acc_s) {
    int t = blockIdx.x * blockDim.x + threadIdx.x;
    int slot = t >> 4;
    if (slot >= 2 * BATCH) return;
    int k = (t & 15) * 4;
    const float* src = (slot < BATCH)
        ? &user_emb[(long)users[slot] * DIM]
        : &item_emb[(long)items[slot - BATCH] * DIM];
    *(float4*)&acc_s[(long)slot * DIM + k] = *(const float4*)&src[k];
}

// ---------------------------------------------------------------------------
// sampled acc update: acc_s[slot] += tab[node] (fp16 -> fp32)
// ---------------------------------------------------------------------------
__global__ void sample_add_kernel(const __half* __restrict__ tab,
                                  const int* __restrict__ users,
                                  const int* __restrict__ items,
                                  float* __restrict__ acc_s) {
    int t = blockIdx.x * blockDim.x + threadIdx.x;
    int slot = t >> 4;
    if (slot >= 2 * BATCH) return;
    int k = (t & 15) * 4;
    int node = (slot < BATCH) ? users[slot] : USER_NUM + items[slot - BATCH];
    float4 x = h4_to_f4(*(const float2*)&tab[(long)node * DIM + k]);
    long o = (long)slot * DIM + k;
    float4 a = *(float4*)&acc_s[o];
    a.x += x.x; a.y += x.y; a.z += x.z; a.w += x.w;
    *(float4*)&acc_s[o] = a;
}

// ---------------------------------------------------------------------------
// K2: per-block LDS hist of dst super-buckets -> global bucket_cnt
// ---------------------------------------------------------------------------
__global__ void bucket_hist_kernel(const int* __restrict__ edge_dst,
                                   int* __restrict__ bucket_cnt) {
    __shared__ int h[NSUP];
    for (int t = threadIdx.x; t < NSUP; t += blockDim.x) h[t] = 0;
    __syncthreads();
    int lo = blockIdx.x * CHUNK;
    int hi = min(lo + CHUNK, NEDGES);
    for (int j = lo + (int)threadIdx.x; j < hi; j += blockDim.x)
        atomicAdd(&h[edge_dst[j] >> 10], 1);
    __syncthreads();
    for (int t = threadIdx.x; t < NSUP; t += blockDim.x)
        if (h[t]) atomicAdd(&bucket_cnt[t], h[t]);
}

// ---------------------------------------------------------------------------
// K3: exclusive scan of bucket_cnt (NSUP=147 <= 256) in one block
// ---------------------------------------------------------------------------
__global__ void bucket_scan_kernel(const int* __restrict__ bucket_cnt,
                                   int* __restrict__ bucket_base,
                                   int* __restrict__ fill,
                                   int* __restrict__ row_ptr) {
    __shared__ int s[256];
    int tid = threadIdx.x;
    int v = (tid < NSUP) ? bucket_cnt[tid] : 0;
    s[tid] = v;
    __syncthreads();
    for (int off = 1; off < 256; off <<= 1) {
        int t = (tid >= off) ? s[tid - off] : 0;
        __syncthreads();
        s[tid] += t;
        __syncthreads();
    }
    if (tid < NSUP) {
        int excl = s[tid] - v;
        bucket_base[tid] = excl;
        fill[tid] = excl;
    }
    if (tid == 0) {
        bucket_base[NSUP] = NEDGES;
        row_ptr[NNODES] = NEDGES;
    }
}

// ---------------------------------------------------------------------------
// K4: partition edges into super-bucket-contiguous packed tmp (8 B/edge)
//     tmp.x = val bits; tmp.y = src | (dst_local << 18)
// ---------------------------------------------------------------------------
__global__ void partition_kernel(const int* __restrict__ edge_src,
                                 const int* __restrict__ edge_dst,
                                 const float* __restrict__ edge_val,
                                 int* __restrict__ fill,
                                 int2* __restrict__ tmp) {
    __shared__ int h[NSUP];
    for (int t = threadIdx.x; t < NSUP; t += blockDim.x) h[t] = 0;
    __syncthreads();
    int lo = blockIdx.x * CHUNK;
    int hi = min(lo + CHUNK, NEDGES);
    for (int j = lo + (int)threadIdx.x; j < hi; j += blockDim.x)
        atomicAdd(&h[edge_dst[j] >> 10], 1);
    __syncthreads();
    for (int t = threadIdx.x; t < NSUP; t += blockDim.x) {
        int c = h[t];
        h[t] = c ? atomicAdd(&fill[t], c) : 0;   // LDS cursor = my base
    }
    __syncthreads();
    for (int j = lo + (int)threadIdx.x; j < hi; j += blockDim.x) {
        int d = edge_dst[j];
        int pos = atomicAdd(&h[d >> 10], 1);
        tmp[pos] = make_int2(__float_as_int(edge_val[j]),
                             edge_src[j] | ((d & (SPN - 1)) << 18));
    }
}

// ---------------------------------------------------------------------------
// K5: per-super local counting sort (1024 nodes, ~16K edges), packed tmp
// ---------------------------------------------------------------------------
__global__ void local_sort_kernel(const int* __restrict__ bucket_base,
                                  const int2* __restrict__ tmp,
                                  int* __restrict__ row_ptr,
                                  int2* __restrict__ sedge) {
    __shared__ int h[SPN];
    __shared__ int cur[SPN];
    __shared__ int ss[256];
    int b = blockIdx.x;
    int base = bucket_base[b];
    int end  = bucket_base[b + 1];
    int tid = threadIdx.x;
    #pragma unroll
    for (int q = 0; q < 4; ++q) h[tid + 256 * q] = 0;
    __syncthreads();
    for (int j = base + tid; j < end; j += 256)
        atomicAdd(&h[(tmp[j].y >> 18) & (SPN - 1)], 1);
    __syncthreads();
    int v0 = h[4 * tid], v1 = h[4 * tid + 1], v2 = h[4 * tid + 2], v3 = h[4 * tid + 3];
    ss[tid] = v0 + v1 + v2 + v3;
    __syncthreads();
    for (int off = 1; off < 256; off <<= 1) {
        int t = (tid >= off) ? ss[tid - off] : 0;
        __syncthreads();
        ss[tid] += t;
        __syncthreads();
    }
    int ebase = (tid > 0) ? ss[tid - 1] : 0;
    int e0 = base + ebase;
    int e1 = e0 + v0;
    int e2 = e1 + v1;
    int e3 = e2 + v2;
    cur[4 * tid]     = e0;
    cur[4 * tid + 1] = e1;
    cur[4 * tid + 2] = e2;
    cur[4 * tid + 3] = e3;
    int n0 = b * SPN + 4 * tid;
    if (n0     < NNODES) row_ptr[n0]     = e0;
    if (n0 + 1 < NNODES) row_ptr[n0 + 1] = e1;
    if (n0 + 2 < NNODES) row_ptr[n0 + 2] = e2;
    if (n0 + 3 < NNODES) row_ptr[n0 + 3] = e3;
    __syncthreads();
    for (int j = base + tid; j < end; j += 256) {
        int2 e = tmp[j];
        int dl = (e.y >> 18) & (SPN - 1);
        int pos = atomicAdd(&cur[dl], 1);
        sedge[pos] = make_int2(e.y & 0x3FFFF, e.x);   // (src, val_bits)
    }
}

// ---------------------------------------------------------------------------
// full gather SpMM (fp16 table): 16 lanes per dst row, unroll x4
// ---------------------------------------------------------------------------
__global__ void spmm_kernel(const int* __restrict__ row_ptr,
                            const int2* __restrict__ sedge,
                            const __half* __restrict__ cur,
                            __half* __restrict__ next) {
    long t = (long)blockIdx.x * blockDim.x + threadIdx.x;
    int row = (int)(t >> 4);
    if (row >= NNODES) return;
    int k = ((int)t & 15) * 4;
    int start = row_ptr[row];
    int end   = row_ptr[row + 1];
    float4 s0 = make_float4(0.f, 0.f, 0.f, 0.f);
    float4 s1 = s0, s2 = s0, s3 = s0;
    int j = start;
    for (; j + 4 <= end; j += 4) {
        int2 e0 = sedge[j];
        int2 e1 = sedge[j + 1];
        int2 e2 = sedge[j + 2];
        int2 e3 = sedge[j + 3];
        float2 r0 = *(const float2*)&cur[(long)e0.x * DIM + k];
        float2 r1 = *(const float2*)&cur[(long)e1.x * DIM + k];
        float2 r2 = *(const float2*)&cur[(long)e2.x * DIM + k];
        float2 r3 = *(const float2*)&cur[(long)e3.x * DIM + k];
        float4 x0 = h4_to_f4(r0), x1 = h4_to_f4(r1);
        float4 x2 = h4_to_f4(r2), x3 = h4_to_f4(r3);
        float v0 = __int_as_float(e0.y), v1 = __int_as_float(e1.y);
        float v2 = __int_as_float(e2.y), v3 = __int_as_float(e3.y);
        s0.x += v0 * x0.x; s0.y += v0 * x0.y; s0.z += v0 * x0.z; s0.w += v0 * x0.w;
        s1.x += v1 * x1.x; s1.y += v1 * x1.y; s1.z += v1 * x1.z; s1.w += v1 * x1.w;
        s2.x += v2 * x2.x; s2.y += v2 * x2.y; s2.z += v2 * x2.z; s2.w += v2 * x2.w;
        s3.x += v3 * x3.x; s3.y += v3 * x3.y; s3.z += v3 * x3.z; s3.w += v3 * x3.w;
    }
    for (; j < end; ++j) {
        int2 e = sedge[j];
        float v = __int_as_float(e.y);
        float4 x = h4_to_f4(*(const float2*)&cur[(long)e.x * DIM + k]);
        s0.x += v * x.x; s0.y += v * x.y; s0.z += v * x.z; s0.w += v * x.w;
    }
    float4 s;
    s.x = (s0.x + s1.x) + (s2.x + s3.x);
    s.y = (s0.y + s1.y) + (s2.y + s3.y);
    s.z = (s0.z + s1.z) + (s2.z + s3.z);
    s.w = (s0.w + s1.w) + (s2.w + s3.w);
    *(float2*)&next[(long)row * DIM + k] = f4_to_h4(s);
}

// ---------------------------------------------------------------------------
// sampled SpMM (layer 3): only the 8192 sampled rows; acc_s += result
// ---------------------------------------------------------------------------
__global__ void spmm_sampled_kernel(const int* __restrict__ row_ptr,
                                    const int2* __restrict__ sedge,
                                    const __half* __restrict__ cur,
                                    const int* __restrict__ users,
                                    const int* __restrict__ items,
                                    float* __restrict__ acc_s) {
    int t = blockIdx.x * blockDim.x + threadIdx.x;
    int slot = t >> 4;
    if (slot >= 2 * BATCH) return;
    int k = (t & 15) * 4;
    int node = (slot < BATCH) ? users[slot] : USER_NUM + items[slot - BATCH];
    int start = row_ptr[node];
    int end   = row_ptr[node + 1];
    float4 s0 = make_float4(0.f, 0.f, 0.f, 0.f);
    float4 s1 = s0, s2 = s0, s3 = s0;
    int j = start;
    for (; j + 4 <= end; j += 4) {
        int2 e0 = sedge[j];
        int2 e1 = sedge[j + 1];
        int2 e2 = sedge[j + 2];
        int2 e3 = sedge[j + 3];
        float4 x0 = h4_to_f4(*(const float2*)&cur[(long)e0.x * DIM + k]);
        float4 x1 = h4_to_f4(*(const float2*)&cur[(long)e1.x * DIM + k]);
        float4 x2 = h4_to_f4(*(const float2*)&cur[(long)e2.x * DIM + k]);
        float4 x3 = h4_to_f4(*(const float2*)&cur[(long)e3.x * DIM + k]);
        float v0 = __int_as_float(e0.y), v1 = __int_as_float(e1.y);
        float v2 = __int_as_float(e2.y), v3 = __int_as_float(e3.y);
        s0.x += v0 * x0.x; s0.y += v0 * x0.y; s0.z += v0 * x0.z; s0.w += v0 * x0.w;
        s1.x += v1 * x1.x; s1.y += v1 * x1.y; s1.z += v1 * x1.z; s1.w += v1 * x1.w;
        s2.x += v2 * x2.x; s2.y += v2 * x2.y; s2.z += v2 * x2.z; s2.w += v2 * x2.w;
        s3.x += v3 * x3.x; s3.y += v3 * x3.y; s3.z += v3 * x3.z; s3.w += v3 * x3.w;
    }
    for (; j < end; ++j) {
        int2 e = sedge[j];
        float v = __int_as_float(e.y);
        float4 x = h4_to_f4(*(const float2*)&cur[(long)e.x * DIM + k]);
        s0.x += v * x.x; s0.y += v * x.y; s0.z += v * x.z; s0.w += v * x.w;
    }
    long o = (long)slot * DIM + k;
    float4 a = *(float4*)&acc_s[o];
    a.x += (s0.x + s1.x) + (s2.x + s3.x);
    a.y += (s0.y + s1.y) + (s2.y + s3.y);
    a.z += (s0.z + s1.z) + (s2.z + s3.z);
    a.w += (s0.w + s1.w) + (s2.w + s3.w);
    *(float4*)&acc_s[o] = a;
}

// ---------------------------------------------------------------------------
// epilogue: one wave per batch elem; gamma = dot(acc_s_u, acc_s_i)/16
// ---------------------------------------------------------------------------
__global__ void dot_kernel(const float* __restrict__ acc_s,
                           float* __restrict__ out) {
    int w = (int)(((long)blockIdx.x * blockDim.x + threadIdx.x) >> 6);
    int lane = threadIdx.x & 63;
    if (w >= BATCH) return;
    float a = acc_s[(long)w * DIM + lane];
    float b = acc_s[(long)(BATCH + w) * DIM + lane];
    float p = a * b;
    #pragma unroll
    for (int off = 32; off; off >>= 1) p += __shfl_down(p, off);
    if (lane == 0) {
        float gamma = p * (1.0f / 16.0f);
        out[w] = 1.0f / (1.0f + __expf(-gamma));
    }
}

extern "C" void kernel_launch(void* const* d_in, const int* in_sizes, int n_in,
                              void* d_out, int out_size, void* d_ws, size_t ws_size,
                              hipStream_t stream) {
    const float* user_emb = (const float*)d_in[0];
    const float* item_emb = (const float*)d_in[1];
    const int*   edge_src = (const int*)d_in[2];
    const int*   edge_dst = (const int*)d_in[3];
    const float* edge_val = (const float*)d_in[4];
    const int*   users    = (const int*)d_in[5];
    const int*   items    = (const int*)d_in[6];
    float* out = (float*)d_out;

    const size_t tbl  = (size_t)NNODES * DIM * sizeof(float);   // 38.4 MB
    const size_t htbl = (size_t)NNODES * DIM * sizeof(__half);  // 19.2 MB
    char* w = (char*)d_ws;
    float*  acc_s       = (float*)w;   w += tbl;   // uses 2 MB of this region
    char*   bufA        = w;           w += tbl;   // tmp int2 (19.2 MB), dead after local_sort
    char*   bufB        = w;           w += tbl;   // tabA + tabB
    int2*   sedge       = (int2*)w;    w += (size_t)NEDGES * 8;
    int*    row_ptr     = (int*)w;     w += ((size_t)NNODES + 16) * 4;
    int*    bucket_cnt  = (int*)w;     w += ((size_t)NSUP + 8) * 4;
    int*    bucket_base = (int*)w;     w += ((size_t)NSUP + 8) * 4;
    int*    fill        = (int*)w;     w += ((size_t)NSUP + 8) * 4;

    int2*   tmp   = (int2*)bufA;
    __half* tabA  = (__half*)bufB;
    __half* tabB  = (__half*)(bufB + htbl);

    // ---- CSR build ----
    hipMemsetAsync(bucket_cnt, 0, (size_t)NSUP * 4, stream);
    bucket_hist_kernel<<<NBLK, 256, 0, stream>>>(edge_dst, bucket_cnt);
    bucket_scan_kernel<<<1, 256, 0, stream>>>(bucket_cnt, bucket_base, fill, row_ptr);
    partition_kernel<<<NBLK, 256, 0, stream>>>(edge_src, edge_dst, edge_val, fill, tmp);
    local_sort_kernel<<<NSUP, 256, 0, stream>>>(bucket_base, tmp, row_ptr, sedge);

    // ---- init ----
    {
        long total4 = (long)NNODES * DIM / 4;
        init_kernel<<<(unsigned)((total4 + 255) / 256), 256, 0, stream>>>(
            user_emb, item_emb, tabA);
    }
    const unsigned samp_grid = (2 * BATCH * 16 + 255) / 256;   // 512 blocks
    sample_init_kernel<<<samp_grid, 256, 0, stream>>>(user_emb, item_emb,
                                                      users, items, acc_s);

    // ---- layers ----
    const unsigned spmm_grid = (unsigned)(((long)NNODES * 16 + 255) / 256);
    spmm_kernel<<<spmm_grid, 256, 0, stream>>>(row_ptr, sedge, tabA, tabB);   // e1
    sample_add_kernel<<<samp_grid, 256, 0, stream>>>(tabB, users, items, acc_s);
    spmm_kernel<<<spmm_grid, 256, 0, stream>>>(row_ptr, sedge, tabB, tabA);   // e2
    sample_add_kernel<<<samp_grid, 256, 0, stream>>>(tabA, users, items, acc_s);
    spmm_sampled_kernel<<<samp_grid, 256, 0, stream>>>(row_ptr, sedge, tabA,
                                                       users, items, acc_s);  // e3 @ samples
    // ---- epilogue ----
    dot_kernel<<<(BATCH * 64 + 255) / 256, 256, 0, stream>>>(acc_s, out);
}

// Round 9
// 242.562 us; speedup vs baseline: 1.0864x; 1.0864x over previous
//
#include <hip/hip_runtime.h>
#include <hip/hip_bf16.h>
#include <hip/hip_fp16.h>

#define USER_NUM 100000
#define ITEM_NUM 50000
#define NNODES   150000
#define DIM      64
#define NEDGES   2400000
#define BATCH    4096

#define SPN      1024                           // nodes per super-bucket (dst>>10)
#define NSUP     ((NNODES + SPN - 1) / SPN)     // 147 super-buckets
#define CHUNK    4096
#define NBLK     ((NEDGES + CHUNK - 1) / CHUNK) // 586 blocks

__device__ inline float4 h4_to_f4(float2 raw) {
    __half2 a = ((__half2*)&raw)[0];
    __half2 b = ((__half2*)&raw)[1];
    float2 fa = __half22float2(a);
    float2 fb = __half22float2(b);
    return make_float4(fa.x, fa.y, fb.x, fb.y);
}

__device__ inline float2 f4_to_h4(float4 s) {
    __half2 a = __floats2half2_rn(s.x, s.y);
    __half2 b = __floats2half2_rn(s.z, s.w);
    float2 st;
    ((__half2*)&st)[0] = a;
    ((__half2*)&st)[1] = b;
    return st;
}

// ---------------------------------------------------------------------------
// init: tabA = concat(user_emb, item_emb) in fp16
// ---------------------------------------------------------------------------
__global__ void init_kernel(const float* __restrict__ user_emb,
                            const float* __restrict__ item_emb,
                            __half* __restrict__ curh) {
    const long total4 = (long)NNODES * DIM / 4;
    long i = (long)blockIdx.x * blockDim.x + threadIdx.x;
    if (i >= total4) return;
    const long user4 = (long)USER_NUM * DIM / 4;
    float4 v;
    if (i < user4) v = ((const float4*)user_emb)[i];
    else           v = ((const float4*)item_emb)[i - user4];
    ((float2*)curh)[i] = f4_to_h4(v);
}

// ---------------------------------------------------------------------------
// sampled acc init: acc_s[slot] = e0 at sampled node (fp32 from orig emb)
// ---------------------------------------------------------------------------
__global__ void sample_init_kernel(const float* __restrict__ user_emb,
                                   const float* __restrict__ item_emb,
                                   const int* __restrict__ users,
                                   const int* __restrict__ items,
                                   float* __restrict__ acc_s) {
    int t = blockIdx.x * blockDim.x + threadIdx.x;
    int slot = t >> 4;
    if (slot >= 2 * BATCH) return;
    int k = (t & 15) * 4;
    const float* src = (slot < BATCH)
        ? &user_emb[(long)users[slot] * DIM]
        : &item_emb[(long)items[slot - BATCH] * DIM];
    *(float4*)&acc_s[(long)slot * DIM + k] = *(const float4*)&src[k];
}

// ---------------------------------------------------------------------------
// sampled acc update: acc_s[slot] += tab[node] (fp16 -> fp32)
// ---------------------------------------------------------------------------
__global__ void sample_add_kernel(const __half* __restrict__ tab,
                                  const int* __restrict__ users,
                                  const int* __restrict__ items,
                                  float* __restrict__ acc_s) {
    int t = blockIdx.x * blockDim.x + threadIdx.x;
    int slot = t >> 4;
    if (slot >= 2 * BATCH) return;
    int k = (t & 15) * 4;
    int node = (slot < BATCH) ? users[slot] : USER_NUM + items[slot - BATCH];
    float4 x = h4_to_f4(*(const float2*)&tab[(long)node * DIM + k]);
    long o = (long)slot * DIM + k;
    float4 a = *(float4*)&acc_s[o];
    a.x += x.x; a.y += x.y; a.z += x.z; a.w += x.w;
    *(float4*)&acc_s[o] = a;
}

// ---------------------------------------------------------------------------
// K2: per-block LDS hist of dst super-buckets -> global bucket_cnt
// ---------------------------------------------------------------------------
__global__ void bucket_hist_kernel(const int* __restrict__ edge_dst,
                                   int* __restrict__ bucket_cnt) {
    __shared__ int h[NSUP];
    for (int t = threadIdx.x; t < NSUP; t += blockDim.x) h[t] = 0;
    __syncthreads();
    int lo = blockIdx.x * CHUNK;
    int hi = min(lo + CHUNK, NEDGES);
    for (int j = lo + (int)threadIdx.x; j < hi; j += blockDim.x)
        atomicAdd(&h[edge_dst[j] >> 10], 1);
    __syncthreads();
    for (int t = threadIdx.x; t < NSUP; t += blockDim.x)
        if (h[t]) atomicAdd(&bucket_cnt[t], h[t]);
}

// ---------------------------------------------------------------------------
// K3: exclusive scan of bucket_cnt (NSUP=147 <= 256) in one block
// ---------------------------------------------------------------------------
__global__ void bucket_scan_kernel(const int* __restrict__ bucket_cnt,
                                   int* __restrict__ bucket_base,
                                   int* __restrict__ fill,
                                   int* __restrict__ row_ptr) {
    __shared__ int s[256];
    int tid = threadIdx.x;
    int v = (tid < NSUP) ? bucket_cnt[tid] : 0;
    s[tid] = v;
    __syncthreads();
    for (int off = 1; off < 256; off <<= 1) {
        int t = (tid >= off) ? s[tid - off] : 0;
        __syncthreads();
        s[tid] += t;
        __syncthreads();
    }
    if (tid < NSUP) {
        int excl = s[tid] - v;
        bucket_base[tid] = excl;
        fill[tid] = excl;
    }
    if (tid == 0) {
        bucket_base[NSUP] = NEDGES;
        row_ptr[NNODES] = NEDGES;
    }
}

// ---------------------------------------------------------------------------
// K4: partition with LDS bucket-staging -> coalesced global writes.
//     pass1: hist; scan -> lbase, reserve global ranges (goff).
//     pass2: scatter packed edges into LDS sout at bucket-sorted local pos.
//     pass3: linear copy-out; bucket via binary search over lbase.
// ---------------------------------------------------------------------------
__global__ __launch_bounds__(256) void partition_kernel(
        const int* __restrict__ edge_src,
        const int* __restrict__ edge_dst,
        const float* __restrict__ edge_val,
        int* __restrict__ fill,
        int2* __restrict__ tmp) {
    __shared__ int cur_[NSUP];
    __shared__ int lbase[NSUP + 1];
    __shared__ int goff[NSUP];
    __shared__ int sc[256];
    __shared__ int2 sout[CHUNK];      // 32 KB
    int tid = threadIdx.x;
    int lo = blockIdx.x * CHUNK;
    int hi = min(lo + CHUNK, NEDGES);
    int n = hi - lo;

    for (int t = tid; t < NSUP; t += 256) cur_[t] = 0;
    __syncthreads();
    // pass1: histogram
    for (int i = tid; i < n; i += 256)
        atomicAdd(&cur_[edge_dst[lo + i] >> 10], 1);
    __syncthreads();
    // scan 147 counts -> local exclusive bases; reserve global ranges
    int c = (tid < NSUP) ? cur_[tid] : 0;
    sc[tid] = c;
    __syncthreads();
    for (int off = 1; off < 256; off <<= 1) {
        int t = (tid >= off) ? sc[tid - off] : 0;
        __syncthreads();
        sc[tid] += t;
        __syncthreads();
    }
    if (tid < NSUP) {
        int excl = sc[tid] - c;
        lbase[tid] = excl;
        goff[tid] = (c ? atomicAdd(&fill[tid], c) : 0) - excl;
    }
    if (tid == 0) lbase[NSUP] = n;
    __syncthreads();
    if (tid < NSUP) cur_[tid] = lbase[tid];
    __syncthreads();
    // pass2: LDS scatter (re-read edges, coalesced & L2-hot)
    for (int i = tid; i < n; i += 256) {
        int d = edge_dst[lo + i];
        int pos = atomicAdd(&cur_[d >> 10], 1);
        sout[pos] = make_int2(__float_as_int(edge_val[lo + i]),
                              edge_src[lo + i] | ((d & (SPN - 1)) << 18));
    }
    __syncthreads();
    // pass3: coalesced copy-out; bucket of slot i via binary search on lbase
    for (int i = tid; i < n; i += 256) {
        int b0 = 0, b1 = NSUP;            // lbase[b0] <= i < lbase[b1]
        while (b1 - b0 > 1) {
            int mid = (b0 + b1) >> 1;
            if (lbase[mid] <= i) b0 = mid; else b1 = mid;
        }
        tmp[goff[b0] + i] = sout[i];
    }
}

// ---------------------------------------------------------------------------
// K5: per-super local counting sort (1024 nodes, ~16K edges), packed tmp
// ---------------------------------------------------------------------------
__global__ void local_sort_kernel(const int* __restrict__ bucket_base,
                                  const int2* __restrict__ tmp,
                                  int* __restrict__ row_ptr,
                                  int2* __restrict__ sedge) {
    __shared__ int h[SPN];
    __shared__ int cur[SPN];
    __shared__ int ss[256];
    int b = blockIdx.x;
    int base = bucket_base[b];
    int end  = bucket_base[b + 1];
    int tid = threadIdx.x;
    #pragma unroll
    for (int q = 0; q < 4; ++q) h[tid + 256 * q] = 0;
    __syncthreads();
    for (int j = base + tid; j < end; j += 256)
        atomicAdd(&h[(tmp[j].y >> 18) & (SPN - 1)], 1);
    __syncthreads();
    int v0 = h[4 * tid], v1 = h[4 * tid + 1], v2 = h[4 * tid + 2], v3 = h[4 * tid + 3];
    ss[tid] = v0 + v1 + v2 + v3;
    __syncthreads();
    for (int off = 1; off < 256; off <<= 1) {
        int t = (tid >= off) ? ss[tid - off] : 0;
        __syncthreads();
        ss[tid] += t;
        __syncthreads();
    }
    int ebase = (tid > 0) ? ss[tid - 1] : 0;
    int e0 = base + ebase;
    int e1 = e0 + v0;
    int e2 = e1 + v1;
    int e3 = e2 + v2;
    cur[4 * tid]     = e0;
    cur[4 * tid + 1] = e1;
    cur[4 * tid + 2] = e2;
    cur[4 * tid + 3] = e3;
    int n0 = b * SPN + 4 * tid;
    if (n0     < NNODES) row_ptr[n0]     = e0;
    if (n0 + 1 < NNODES) row_ptr[n0 + 1] = e1;
    if (n0 + 2 < NNODES) row_ptr[n0 + 2] = e2;
    if (n0 + 3 < NNODES) row_ptr[n0 + 3] = e3;
    __syncthreads();
    for (int j = base + tid; j < end; j += 256) {
        int2 e = tmp[j];
        int dl = (e.y >> 18) & (SPN - 1);
        int pos = atomicAdd(&cur[dl], 1);
        sedge[pos] = make_int2(e.y & 0x3FFFF, e.x);   // (src, val_bits)
    }
}

// ---------------------------------------------------------------------------
// full gather SpMM (fp16 table): 16 lanes per dst row, unroll x4
// ---------------------------------------------------------------------------
__global__ void spmm_kernel(const int* __restrict__ row_ptr,
                            const int2* __restrict__ sedge,
                            const __half* __restrict__ cur,
                            __half* __restrict__ next) {
    long t = (long)blockIdx.x * blockDim.x + threadIdx.x;
    int row = (int)(t >> 4);
    if (row >= NNODES) return;
    int k = ((int)t & 15) * 4;
    int start = row_ptr[row];
    int end   = row_ptr[row + 1];
    float4 s0 = make_float4(0.f, 0.f, 0.f, 0.f);
    float4 s1 = s0, s2 = s0, s3 = s0;
    int j = start;
    for (; j + 4 <= end; j += 4) {
        int2 e0 = sedge[j];
        int2 e1 = sedge[j + 1];
        int2 e2 = sedge[j + 2];
        int2 e3 = sedge[j + 3];
        float2 r0 = *(const float2*)&cur[(long)e0.x * DIM + k];
        float2 r1 = *(const float2*)&cur[(long)e1.x * DIM + k];
        float2 r2 = *(const float2*)&cur[(long)e2.x * DIM + k];
        float2 r3 = *(const float2*)&cur[(long)e3.x * DIM + k];
        float4 x0 = h4_to_f4(r0), x1 = h4_to_f4(r1);
        float4 x2 = h4_to_f4(r2), x3 = h4_to_f4(r3);
        float v0 = __int_as_float(e0.y), v1 = __int_as_float(e1.y);
        float v2 = __int_as_float(e2.y), v3 = __int_as_float(e3.y);
        s0.x += v0 * x0.x; s0.y += v0 * x0.y; s0.z += v0 * x0.z; s0.w += v0 * x0.w;
        s1.x += v1 * x1.x; s1.y += v1 * x1.y; s1.z += v1 * x1.z; s1.w += v1 * x1.w;
        s2.x += v2 * x2.x; s2.y += v2 * x2.y; s2.z += v2 * x2.z; s2.w += v2 * x2.w;
        s3.x += v3 * x3.x; s3.y += v3 * x3.y; s3.z += v3 * x3.z; s3.w += v3 * x3.w;
    }
    for (; j < end; ++j) {
        int2 e = sedge[j];
        float v = __int_as_float(e.y);
        float4 x = h4_to_f4(*(const float2*)&cur[(long)e.x * DIM + k]);
        s0.x += v * x.x; s0.y += v * x.y; s0.z += v * x.z; s0.w += v * x.w;
    }
    float4 s;
    s.x = (s0.x + s1.x) + (s2.x + s3.x);
    s.y = (s0.y + s1.y) + (s2.y + s3.y);
    s.z = (s0.z + s1.z) + (s2.z + s3.z);
    s.w = (s0.w + s1.w) + (s2.w + s3.w);
    *(float2*)&next[(long)row * DIM + k] = f4_to_h4(s);
}

// ---------------------------------------------------------------------------
// sampled SpMM (layer 3): only the 8192 sampled rows; acc_s += result
// ---------------------------------------------------------------------------
__global__ void spmm_sampled_kernel(const int* __restrict__ row_ptr,
                                    const int2* __restrict__ sedge,
                                    const __half* __restrict__ cur,
                                    const int* __restrict__ users,
                                    const int* __restrict__ items,
                                    float* __restrict__ acc_s) {
    int t = blockIdx.x * blockDim.x + threadIdx.x;
    int slot = t >> 4;
    if (slot >= 2 * BATCH) return;
    int k = (t & 15) * 4;
    int node = (slot < BATCH) ? users[slot] : USER_NUM + items[slot - BATCH];
    int start = row_ptr[node];
    int end   = row_ptr[node + 1];
    float4 s0 = make_float4(0.f, 0.f, 0.f, 0.f);
    float4 s1 = s0, s2 = s0, s3 = s0;
    int j = start;
    for (; j + 4 <= end; j += 4) {
        int2 e0 = sedge[j];
        int2 e1 = sedge[j + 1];
        int2 e2 = sedge[j + 2];
        int2 e3 = sedge[j + 3];
        float4 x0 = h4_to_f4(*(const float2*)&cur[(long)e0.x * DIM + k]);
        float4 x1 = h4_to_f4(*(const float2*)&cur[(long)e1.x * DIM + k]);
        float4 x2 = h4_to_f4(*(const float2*)&cur[(long)e2.x * DIM + k]);
        float4 x3 = h4_to_f4(*(const float2*)&cur[(long)e3.x * DIM + k]);
        float v0 = __int_as_float(e0.y), v1 = __int_as_float(e1.y);
        float v2 = __int_as_float(e2.y), v3 = __int_as_float(e3.y);
        s0.x += v0 * x0.x; s0.y += v0 * x0.y; s0.z += v0 * x0.z; s0.w += v0 * x0.w;
        s1.x += v1 * x1.x; s1.y += v1 * x1.y; s1.z += v1 * x1.z; s1.w += v1 * x1.w;
        s2.x += v2 * x2.x; s2.y += v2 * x2.y; s2.z += v2 * x2.z; s2.w += v2 * x2.w;
        s3.x += v3 * x3.x; s3.y += v3 * x3.y; s3.z += v3 * x3.z; s3.w += v3 * x3.w;
    }
    for (; j < end; ++j) {
        int2 e = sedge[j];
        float v = __int_as_float(e.y);
        float4 x = h4_to_f4(*(const float2*)&cur[(long)e.x * DIM + k]);
        s0.x += v * x.x; s0.y += v * x.y; s0.z += v * x.z; s0.w += v * x.w;
    }
    long o = (long)slot * DIM + k;
    float4 a = *(float4*)&acc_s[o];
    a.x += (s0.x + s1.x) + (s2.x + s3.x);
    a.y += (s0.y + s1.y) + (s2.y + s3.y);
    a.z += (s0.z + s1.z) + (s2.z + s3.z);
    a.w += (s0.w + s1.w) + (s2.w + s3.w);
    *(float4*)&acc_s[o] = a;
}

// ---------------------------------------------------------------------------
// epilogue: one wave per batch elem; gamma = dot(acc_s_u, acc_s_i)/16
// ---------------------------------------------------------------------------
__global__ void dot_kernel(const float* __restrict__ acc_s,
                           float* __restrict__ out) {
    int w = (int)(((long)blockIdx.x * blockDim.x + threadIdx.x) >> 6);
    int lane = threadIdx.x & 63;
    if (w >= BATCH) return;
    float a = acc_s[(long)w * DIM + lane];
    float b = acc_s[(long)(BATCH + w) * DIM + lane];
    float p = a * b;
    #pragma unroll
    for (int off = 32; off; off >>= 1) p += __shfl_down(p, off);
    if (lane == 0) {
        float gamma = p * (1.0f / 16.0f);
        out[w] = 1.0f / (1.0f + __expf(-gamma));
    }
}

extern "C" void kernel_launch(void* const* d_in, const int* in_sizes, int n_in,
                              void* d_out, int out_size, void* d_ws, size_t ws_size,
                              hipStream_t stream) {
    const float* user_emb = (const float*)d_in[0];
    const float* item_emb = (const float*)d_in[1];
    const int*   edge_src = (const int*)d_in[2];
    const int*   edge_dst = (const int*)d_in[3];
    const float* edge_val = (const float*)d_in[4];
    const int*   users    = (const int*)d_in[5];
    const int*   items    = (const int*)d_in[6];
    float* out = (float*)d_out;

    const size_t tbl  = (size_t)NNODES * DIM * sizeof(float);   // 38.4 MB
    const size_t htbl = (size_t)NNODES * DIM * sizeof(__half);  // 19.2 MB
    char* w = (char*)d_ws;
    float*  acc_s       = (float*)w;   w += tbl;   // uses 2 MB of this region
    char*   bufA        = w;           w += tbl;   // tmp int2 (19.2 MB), dead after local_sort
    char*   bufB        = w;           w += tbl;   // tabA + tabB
    int2*   sedge       = (int2*)w;    w += (size_t)NEDGES * 8;
    int*    row_ptr     = (int*)w;     w += ((size_t)NNODES + 16) * 4;
    int*    bucket_cnt  = (int*)w;     w += ((size_t)NSUP + 8) * 4;
    int*    bucket_base = (int*)w;     w += ((size_t)NSUP + 8) * 4;
    int*    fill        = (int*)w;     w += ((size_t)NSUP + 8) * 4;

    int2*   tmp   = (int2*)bufA;
    __half* tabA  = (__half*)bufB;
    __half* tabB  = (__half*)(bufB + htbl);

    // ---- CSR build ----
    hipMemsetAsync(bucket_cnt, 0, (size_t)NSUP * 4, stream);
    bucket_hist_kernel<<<NBLK, 256, 0, stream>>>(edge_dst, bucket_cnt);
    bucket_scan_kernel<<<1, 256, 0, stream>>>(bucket_cnt, bucket_base, fill, row_ptr);
    partition_kernel<<<NBLK, 256, 0, stream>>>(edge_src, edge_dst, edge_val, fill, tmp);
    local_sort_kernel<<<NSUP, 256, 0, stream>>>(bucket_base, tmp, row_ptr, sedge);

    // ---- init ----
    {
        long total4 = (long)NNODES * DIM / 4;
        init_kernel<<<(unsigned)((total4 + 255) / 256), 256, 0, stream>>>(
            user_emb, item_emb, tabA);
    }
    const unsigned samp_grid = (2 * BATCH * 16 + 255) / 256;   // 512 blocks
    sample_init_kernel<<<samp_grid, 256, 0, stream>>>(user_emb, item_emb,
                                                      users, items, acc_s);

    // ---- layers ----
    const unsigned spmm_grid = (unsigned)(((long)NNODES * 16 + 255) / 256);
    spmm_kernel<<<spmm_grid, 256, 0, stream>>>(row_ptr, sedge, tabA, tabB);   // e1
    sample_add_kernel<<<samp_grid, 256, 0, stream>>>(tabB, users, items, acc_s);
    spmm_kernel<<<spmm_grid, 256, 0, stream>>>(row_ptr, sedge, tabB, tabA);   // e2
    sample_add_kernel<<<samp_grid, 256, 0, stream>>>(tabA, users, items, acc_s);
    spmm_sampled_kernel<<<samp_grid, 256, 0, stream>>>(row_ptr, sedge, tabA,
                                                       users, items, acc_s);  // e3 @ samples
    // ---- epilogue ----
    dot_kernel<<<(BATCH * 64 + 255) / 256, 256, 0, stream>>>(acc_s, out);
}

// Round 10
// 233.984 us; speedup vs baseline: 1.1263x; 1.0367x over previous
//
#include <hip/hip_runtime.h>
#include <hip/hip_bf16.h>
#include <hip/hip_fp16.h>

#define USER_NUM 100000
#define ITEM_NUM 50000
#define NNODES   150000
#define DIM      64
#define NEDGES   2400000
#define BATCH    4096

#define SPN      1024                           // nodes per super-bucket (dst>>10)
#define NSUP     ((NNODES + SPN - 1) / SPN)     // 147 super-buckets
#define NSUPP    160                            // padded stride for blockhist
#define CHUNK    4096
#define NBLK     ((NEDGES + CHUNK - 1) / CHUNK) // 586 blocks

__device__ inline float4 h4_to_f4(float2 raw) {
    __half2 a = ((__half2*)&raw)[0];
    __half2 b = ((__half2*)&raw)[1];
    float2 fa = __half22float2(a);
    float2 fb = __half22float2(b);
    return make_float4(fa.x, fa.y, fb.x, fb.y);
}

__device__ inline float2 f4_to_h4(float4 s) {
    __half2 a = __floats2half2_rn(s.x, s.y);
    __half2 b = __floats2half2_rn(s.z, s.w);
    float2 st;
    ((__half2*)&st)[0] = a;
    ((__half2*)&st)[1] = b;
    return st;
}

// ---------------------------------------------------------------------------
// init: tabA = concat(user_emb, item_emb) in fp16
// ---------------------------------------------------------------------------
__global__ void init_kernel(const float* __restrict__ user_emb,
                            const float* __restrict__ item_emb,
                            __half* __restrict__ curh) {
    const long total4 = (long)NNODES * DIM / 4;
    long i = (long)blockIdx.x * blockDim.x + threadIdx.x;
    if (i >= total4) return;
    const long user4 = (long)USER_NUM * DIM / 4;
    float4 v;
    if (i < user4) v = ((const float4*)user_emb)[i];
    else           v = ((const float4*)item_emb)[i - user4];
    ((float2*)curh)[i] = f4_to_h4(v);
}

// ---------------------------------------------------------------------------
// sampled acc init: acc_s[slot] = e0 at sampled node (fp32 from orig emb)
// ---------------------------------------------------------------------------
__global__ void sample_init_kernel(const float* __restrict__ user_emb,
                                   const float* __restrict__ item_emb,
                                   const int* __restrict__ users,
                                   const int* __restrict__ items,
                                   float* __restrict__ acc_s) {
    int t = blockIdx.x * blockDim.x + threadIdx.x;
    int slot = t >> 4;
    if (slot >= 2 * BATCH) return;
    int k = (t & 15) * 4;
    const float* src = (slot < BATCH)
        ? &user_emb[(long)users[slot] * DIM]
        : &item_emb[(long)items[slot - BATCH] * DIM];
    *(float4*)&acc_s[(long)slot * DIM + k] = *(const float4*)&src[k];
}

// ---------------------------------------------------------------------------
// sampled acc update: acc_s[slot] += tab[node] (fp16 -> fp32)
// ---------------------------------------------------------------------------
__global__ void sample_add_kernel(const __half* __restrict__ tab,
                                  const int* __restrict__ users,
                                  const int* __restrict__ items,
                                  float* __restrict__ acc_s) {
    int t = blockIdx.x * blockDim.x + threadIdx.x;
    int slot = t >> 4;
    if (slot >= 2 * BATCH) return;
    int k = (t & 15) * 4;
    int node = (slot < BATCH) ? users[slot] : USER_NUM + items[slot - BATCH];
    float4 x = h4_to_f4(*(const float2*)&tab[(long)node * DIM + k]);
    long o = (long)slot * DIM + k;
    float4 a = *(float4*)&acc_s[o];
    a.x += x.x; a.y += x.y; a.z += x.z; a.w += x.w;
    *(float4*)&acc_s[o] = a;
}

// ---------------------------------------------------------------------------
// K2: per-block LDS hist of dst super-buckets -> bucket_cnt + per-block hist
// ---------------------------------------------------------------------------
__global__ void bucket_hist_kernel(const int* __restrict__ edge_dst,
                                   int* __restrict__ bucket_cnt,
                                   int* __restrict__ blockhist) {
    __shared__ int h[NSUP];
    for (int t = threadIdx.x; t < NSUP; t += blockDim.x) h[t] = 0;
    __syncthreads();
    int lo = blockIdx.x * CHUNK;
    int hi = min(lo + CHUNK, NEDGES);
    for (int j = lo + (int)threadIdx.x; j < hi; j += blockDim.x)
        atomicAdd(&h[edge_dst[j] >> 10], 1);
    __syncthreads();
    for (int t = threadIdx.x; t < NSUP; t += blockDim.x) {
        int c = h[t];
        blockhist[blockIdx.x * NSUPP + t] = c;
        if (c) atomicAdd(&bucket_cnt[t], c);
    }
}

// ---------------------------------------------------------------------------
// K3: exclusive scan of bucket_cnt (NSUP=147 <= 256) in one block
// ---------------------------------------------------------------------------
__global__ void bucket_scan_kernel(const int* __restrict__ bucket_cnt,
                                   int* __restrict__ bucket_base,
                                   int* __restrict__ fill,
                                   int* __restrict__ row_ptr) {
    __shared__ int s[256];
    int tid = threadIdx.x;
    int v = (tid < NSUP) ? bucket_cnt[tid] : 0;
    s[tid] = v;
    __syncthreads();
    for (int off = 1; off < 256; off <<= 1) {
        int t = (tid >= off) ? s[tid - off] : 0;
        __syncthreads();
        s[tid] += t;
        __syncthreads();
    }
    if (tid < NSUP) {
        int excl = s[tid] - v;
        bucket_base[tid] = excl;
        fill[tid] = excl;
    }
    if (tid == 0) {
        bucket_base[NSUP] = NEDGES;
        row_ptr[NNODES] = NEDGES;
    }
}

// ---------------------------------------------------------------------------
// K4: partition, LDS-staged with coalesced global writes.
//     - local hist comes precomputed from bucket_hist (blockhist row)
//     - pass2: scatter packed edges into LDS sout; record bucket in sbkt (u8)
//     - pass3: linear copy-out, bucket via one LDS byte read
// ---------------------------------------------------------------------------
__global__ __launch_bounds__(256) void partition_kernel(
        const int* __restrict__ edge_src,
        const int* __restrict__ edge_dst,
        const float* __restrict__ edge_val,
        const int* __restrict__ blockhist,
        int* __restrict__ fill,
        int2* __restrict__ tmp) {
    __shared__ int cur_[NSUP];
    __shared__ int goff[NSUP];
    __shared__ int sc[256];
    __shared__ unsigned char sbkt[CHUNK];   // 4 KB
    __shared__ int2 sout[CHUNK];            // 32 KB
    int tid = threadIdx.x;
    int lo = blockIdx.x * CHUNK;
    int hi = min(lo + CHUNK, NEDGES);
    int n = hi - lo;

    // local exclusive scan of this block's precomputed hist
    int c = (tid < NSUP) ? blockhist[blockIdx.x * NSUPP + tid] : 0;
    sc[tid] = c;
    __syncthreads();
    for (int off = 1; off < 256; off <<= 1) {
        int t = (tid >= off) ? sc[tid - off] : 0;
        __syncthreads();
        sc[tid] += t;
        __syncthreads();
    }
    if (tid < NSUP) {
        int excl = sc[tid] - c;
        cur_[tid] = excl;
        goff[tid] = (c ? atomicAdd(&fill[tid], c) : 0) - excl;
    }
    __syncthreads();
    // pass2: LDS scatter
    for (int i = tid; i < n; i += 256) {
        int d = edge_dst[lo + i];
        int b = d >> 10;
        int pos = atomicAdd(&cur_[b], 1);
        sout[pos] = make_int2(__float_as_int(edge_val[lo + i]),
                              edge_src[lo + i] | ((d & (SPN - 1)) << 18));
        sbkt[pos] = (unsigned char)b;
    }
    __syncthreads();
    // pass3: coalesced copy-out
    for (int i = tid; i < n; i += 256) {
        int b = sbkt[i];
        tmp[goff[b] + i] = sout[i];
    }
}

// ---------------------------------------------------------------------------
// K5: per-super local counting sort (1024 nodes, ~16K edges), packed tmp
// ---------------------------------------------------------------------------
__global__ void local_sort_kernel(const int* __restrict__ bucket_base,
                                  const int2* __restrict__ tmp,
                                  int* __restrict__ row_ptr,
                                  int2* __restrict__ sedge) {
    __shared__ int h[SPN];
    __shared__ int cur[SPN];
    __shared__ int ss[256];
    int b = blockIdx.x;
    int base = bucket_base[b];
    int end  = bucket_base[b + 1];
    int tid = threadIdx.x;
    #pragma unroll
    for (int q = 0; q < 4; ++q) h[tid + 256 * q] = 0;
    __syncthreads();
    for (int j = base + tid; j < end; j += 256)
        atomicAdd(&h[(tmp[j].y >> 18) & (SPN - 1)], 1);
    __syncthreads();
    int v0 = h[4 * tid], v1 = h[4 * tid + 1], v2 = h[4 * tid + 2], v3 = h[4 * tid + 3];
    ss[tid] = v0 + v1 + v2 + v3;
    __syncthreads();
    for (int off = 1; off < 256; off <<= 1) {
        int t = (tid >= off) ? ss[tid - off] : 0;
        __syncthreads();
        ss[tid] += t;
        __syncthreads();
    }
    int ebase = (tid > 0) ? ss[tid - 1] : 0;
    int e0 = base + ebase;
    int e1 = e0 + v0;
    int e2 = e1 + v1;
    int e3 = e2 + v2;
    cur[4 * tid]     = e0;
    cur[4 * tid + 1] = e1;
    cur[4 * tid + 2] = e2;
    cur[4 * tid + 3] = e3;
    int n0 = b * SPN + 4 * tid;
    if (n0     < NNODES) row_ptr[n0]     = e0;
    if (n0 + 1 < NNODES) row_ptr[n0 + 1] = e1;
    if (n0 + 2 < NNODES) row_ptr[n0 + 2] = e2;
    if (n0 + 3 < NNODES) row_ptr[n0 + 3] = e3;
    __syncthreads();
    for (int j = base + tid; j < end; j += 256) {
        int2 e = tmp[j];
        int dl = (e.y >> 18) & (SPN - 1);
        int pos = atomicAdd(&cur[dl], 1);
        sedge[pos] = make_int2(e.y & 0x3FFFF, e.x);   // (src, val_bits)
    }
}

// ---------------------------------------------------------------------------
// full gather SpMM (fp16 table): 8 lanes per dst row, 16 B (8 halfs) per lane.
// Unroll x4: 4 independent 16-B gathers in flight.
// ---------------------------------------------------------------------------
__global__ void spmm_kernel(const int* __restrict__ row_ptr,
                            const int2* __restrict__ sedge,
                            const __half* __restrict__ cur,
                            __half* __restrict__ next) {
    long t = (long)blockIdx.x * blockDim.x + threadIdx.x;
    int row = (int)(t >> 3);
    if (row >= NNODES) return;
    int k = ((int)t & 7) * 8;
    int start = row_ptr[row];
    int end   = row_ptr[row + 1];
    float a0[8], a1[8], a2[8], a3[8];
    #pragma unroll
    for (int q = 0; q < 8; ++q) { a0[q] = 0.f; a1[q] = 0.f; a2[q] = 0.f; a3[q] = 0.f; }
    int j = start;
    for (; j + 4 <= end; j += 4) {
        int2 e0 = sedge[j];
        int2 e1 = sedge[j + 1];
        int2 e2 = sedge[j + 2];
        int2 e3 = sedge[j + 3];
        float4 r0 = *(const float4*)&cur[(long)e0.x * DIM + k];
        float4 r1 = *(const float4*)&cur[(long)e1.x * DIM + k];
        float4 r2 = *(const float4*)&cur[(long)e2.x * DIM + k];
        float4 r3 = *(const float4*)&cur[(long)e3.x * DIM + k];
        float v0 = __int_as_float(e0.y), v1 = __int_as_float(e1.y);
        float v2 = __int_as_float(e2.y), v3 = __int_as_float(e3.y);
        const __half2* h0 = (const __half2*)&r0;
        const __half2* h1 = (const __half2*)&r1;
        const __half2* h2 = (const __half2*)&r2;
        const __half2* h3 = (const __half2*)&r3;
        #pragma unroll
        for (int q = 0; q < 4; ++q) {
            float2 f0 = __half22float2(h0[q]);
            float2 f1 = __half22float2(h1[q]);
            float2 f2 = __half22float2(h2[q]);
            float2 f3 = __half22float2(h3[q]);
            a0[2*q]   += v0 * f0.x;  a0[2*q+1] += v0 * f0.y;
            a1[2*q]   += v1 * f1.x;  a1[2*q+1] += v1 * f1.y;
            a2[2*q]   += v2 * f2.x;  a2[2*q+1] += v2 * f2.y;
            a3[2*q]   += v3 * f3.x;  a3[2*q+1] += v3 * f3.y;
        }
    }
    for (; j < end; ++j) {
        int2 e = sedge[j];
        float v = __int_as_float(e.y);
        float4 r = *(const float4*)&cur[(long)e.x * DIM + k];
        const __half2* h = (const __half2*)&r;
        #pragma unroll
        for (int q = 0; q < 4; ++q) {
            float2 f = __half22float2(h[q]);
            a0[2*q]   += v * f.x;
            a0[2*q+1] += v * f.y;
        }
    }
    float4 st;
    __half2* sh = (__half2*)&st;
    #pragma unroll
    for (int q = 0; q < 4; ++q) {
        float lo = (a0[2*q]   + a1[2*q])   + (a2[2*q]   + a3[2*q]);
        float hi = (a0[2*q+1] + a1[2*q+1]) + (a2[2*q+1] + a3[2*q+1]);
        sh[q] = __floats2half2_rn(lo, hi);
    }
    *(float4*)&next[(long)row * DIM + k] = st;
}

// ---------------------------------------------------------------------------
// sampled SpMM (layer 3): only the 8192 sampled rows; acc_s += result
// ---------------------------------------------------------------------------
__global__ void spmm_sampled_kernel(const int* __restrict__ row_ptr,
                                    const int2* __restrict__ sedge,
                                    const __half* __restrict__ cur,
                                    const int* __restrict__ users,
                                    const int* __restrict__ items,
                                    float* __restrict__ acc_s) {
    int t = blockIdx.x * blockDim.x + threadIdx.x;
    int slot = t >> 4;
    if (slot >= 2 * BATCH) return;
    int k = (t & 15) * 4;
    int node = (slot < BATCH) ? users[slot] : USER_NUM + items[slot - BATCH];
    int start = row_ptr[node];
    int end   = row_ptr[node + 1];
    float4 s0 = make_float4(0.f, 0.f, 0.f, 0.f);
    float4 s1 = s0, s2 = s0, s3 = s0;
    int j = start;
    for (; j + 4 <= end; j += 4) {
        int2 e0 = sedge[j];
        int2 e1 = sedge[j + 1];
        int2 e2 = sedge[j + 2];
        int2 e3 = sedge[j + 3];
        float4 x0 = h4_to_f4(*(const float2*)&cur[(long)e0.x * DIM + k]);
        float4 x1 = h4_to_f4(*(const float2*)&cur[(long)e1.x * DIM + k]);
        float4 x2 = h4_to_f4(*(const float2*)&cur[(long)e2.x * DIM + k]);
        float4 x3 = h4_to_f4(*(const float2*)&cur[(long)e3.x * DIM + k]);
        float v0 = __int_as_float(e0.y), v1 = __int_as_float(e1.y);
        float v2 = __int_as_float(e2.y), v3 = __int_as_float(e3.y);
        s0.x += v0 * x0.x; s0.y += v0 * x0.y; s0.z += v0 * x0.z; s0.w += v0 * x0.w;
        s1.x += v1 * x1.x; s1.y += v1 * x1.y; s1.z += v1 * x1.z; s1.w += v1 * x1.w;
        s2.x += v2 * x2.x; s2.y += v2 * x2.y; s2.z += v2 * x2.z; s2.w += v2 * x2.w;
        s3.x += v3 * x3.x; s3.y += v3 * x3.y; s3.z += v3 * x3.z; s3.w += v3 * x3.w;
    }
    for (; j < end; ++j) {
        int2 e = sedge[j];
        float v = __int_as_float(e.y);
        float4 x = h4_to_f4(*(const float2*)&cur[(long)e.x * DIM + k]);
        s0.x += v * x.x; s0.y += v * x.y; s0.z += v * x.z; s0.w += v * x.w;
    }
    long o = (long)slot * DIM + k;
    float4 a = *(float4*)&acc_s[o];
    a.x += (s0.x + s1.x) + (s2.x + s3.x);
    a.y += (s0.y + s1.y) + (s2.y + s3.y);
    a.z += (s0.z + s1.z) + (s2.z + s3.z);
    a.w += (s0.w + s1.w) + (s2.w + s3.w);
    *(float4*)&acc_s[o] = a;
}

// ---------------------------------------------------------------------------
// epilogue: one wave per batch elem; gamma = dot(acc_s_u, acc_s_i)/16
// ---------------------------------------------------------------------------
__global__ void dot_kernel(const float* __restrict__ acc_s,
                           float* __restrict__ out) {
    int w = (int)(((long)blockIdx.x * blockDim.x + threadIdx.x) >> 6);
    int lane = threadIdx.x & 63;
    if (w >= BATCH) return;
    float a = acc_s[(long)w * DIM + lane];
    float b = acc_s[(long)(BATCH + w) * DIM + lane];
    float p = a * b;
    #pragma unroll
    for (int off = 32; off; off >>= 1) p += __shfl_down(p, off);
    if (lane == 0) {
        float gamma = p * (1.0f / 16.0f);
        out[w] = 1.0f / (1.0f + __expf(-gamma));
    }
}

extern "C" void kernel_launch(void* const* d_in, const int* in_sizes, int n_in,
                              void* d_out, int out_size, void* d_ws, size_t ws_size,
                              hipStream_t stream) {
    const float* user_emb = (const float*)d_in[0];
    const float* item_emb = (const float*)d_in[1];
    const int*   edge_src = (const int*)d_in[2];
    const int*   edge_dst = (const int*)d_in[3];
    const float* edge_val = (const float*)d_in[4];
    const int*   users    = (const int*)d_in[5];
    const int*   items    = (const int*)d_in[6];
    float* out = (float*)d_out;

    const size_t tbl  = (size_t)NNODES * DIM * sizeof(float);   // 38.4 MB
    const size_t htbl = (size_t)NNODES * DIM * sizeof(__half);  // 19.2 MB
    char* w = (char*)d_ws;
    float*  acc_s       = (float*)w;   w += tbl;   // uses 2 MB of this region
    char*   bufA        = w;           w += tbl;   // tmp int2 (19.2 MB), dead after local_sort
    char*   bufB        = w;           w += tbl;   // tabA + tabB
    int2*   sedge       = (int2*)w;    w += (size_t)NEDGES * 8;
    int*    row_ptr     = (int*)w;     w += ((size_t)NNODES + 16) * 4;
    int*    bucket_cnt  = (int*)w;     w += ((size_t)NSUP + 8) * 4;
    int*    bucket_base = (int*)w;     w += ((size_t)NSUP + 8) * 4;
    int*    fill        = (int*)w;     w += ((size_t)NSUP + 8) * 4;
    int*    blockhist   = (int*)w;     w += (size_t)NBLK * NSUPP * 4;  // 375 KB

    int2*   tmp   = (int2*)bufA;
    __half* tabA  = (__half*)bufB;
    __half* tabB  = (__half*)(bufB + htbl);

    // ---- CSR build ----
    hipMemsetAsync(bucket_cnt, 0, (size_t)NSUP * 4, stream);
    bucket_hist_kernel<<<NBLK, 256, 0, stream>>>(edge_dst, bucket_cnt, blockhist);
    bucket_scan_kernel<<<1, 256, 0, stream>>>(bucket_cnt, bucket_base, fill, row_ptr);
    partition_kernel<<<NBLK, 256, 0, stream>>>(edge_src, edge_dst, edge_val,
                                               blockhist, fill, tmp);
    local_sort_kernel<<<NSUP, 256, 0, stream>>>(bucket_base, tmp, row_ptr, sedge);

    // ---- init ----
    {
        long total4 = (long)NNODES * DIM / 4;
        init_kernel<<<(unsigned)((total4 + 255) / 256), 256, 0, stream>>>(
            user_emb, item_emb, tabA);
    }
    const unsigned samp_grid = (2 * BATCH * 16 + 255) / 256;   // 512 blocks
    sample_init_kernel<<<samp_grid, 256, 0, stream>>>(user_emb, item_emb,
                                                      users, items, acc_s);

    // ---- layers ----
    const unsigned spmm_grid = (unsigned)(((long)NNODES * 8 + 255) / 256);
    spmm_kernel<<<spmm_grid, 256, 0, stream>>>(row_ptr, sedge, tabA, tabB);   // e1
    sample_add_kernel<<<samp_grid, 256, 0, stream>>>(tabB, users, items, acc_s);
    spmm_kernel<<<spmm_grid, 256, 0, stream>>>(row_ptr, sedge, tabB, tabA);   // e2
    sample_add_kernel<<<samp_grid, 256, 0, stream>>>(tabA, users, items, acc_s);
    spmm_sampled_kernel<<<samp_grid, 256, 0, stream>>>(row_ptr, sedge, tabA,
                                                       users, items, acc_s);  // e3 @ samples
    // ---- epilogue ----
    dot_kernel<<<(BATCH * 64 + 255) / 256, 256, 0, stream>>>(acc_s, out);
}